// Round 1
// baseline (314.264 us; speedup 1.0000x reference)
//
#include <hip/hip_runtime.h>
#include <cstdint>
#include <cstddef>

// Problem constants
constexpr int DD = 1024;        // D
constexpr int TT = 4096;        // T
constexpr int BB = 4;           // B
constexpr int MM = BB * TT;     // 16384 rows

typedef __bf16 bf16x8 __attribute__((ext_vector_type(8)));
typedef float  f32x4  __attribute__((ext_vector_type(4)));

__device__ __forceinline__ unsigned short f2bf(float f) {
  union { float f; uint32_t u; } c; c.f = f;
  uint32_t r = (c.u + 0x7FFFu + ((c.u >> 16) & 1u)) >> 16;
  return (unsigned short)r;
}

__device__ __forceinline__ float fast_rcp(float x) {
  return __builtin_amdgcn_rcpf(x);
}

// async global->LDS 16B per lane; lds_dst must be wave-uniform (HW adds lane*16)
__device__ __forceinline__ void async_ld16(const unsigned short* g, unsigned short* lds_dst) {
  __builtin_amdgcn_global_load_lds(
      (const __attribute__((address_space(1))) void*)g,
      (__attribute__((address_space(3))) void*)lds_dst,
      16, 0, 0);
}

// st_16x32-style LDS swizzle: XOR byte-bit-5 with byte-bit-9 (involution,
// 16B-block-preserving). Applied to plane-relative offsets; planes 1KB-aligned.
__device__ __forceinline__ int swz(int b) { return b ^ (((b >> 9) & 1) << 5); }

// ---------------------------------------------------------------------------
// Merged prep: blocks [0,1024) fold time-mix into weights (wave per row) and
// accumulate bias dots; blocks [1024, 1024+16384) convert x to bf16 and emit
// x[:, T-1, :].
__global__ void prep_all(const float* __restrict__ Wk, const float* __restrict__ Wv,
                         const float* __restrict__ Wr, const float* __restrict__ Wo,
                         const float* __restrict__ tmk, const float* __restrict__ tmv,
                         const float* __restrict__ tmr,
                         const float* __restrict__ last_x,
                         const float4* __restrict__ x,
                         unsigned short* __restrict__ wz,   // [3][1024][1024] bf16
                         unsigned short* __restrict__ wo,   // [1024][1024] bf16
                         float* __restrict__ bias,          // [3][1024]
                         ushort4* __restrict__ xb,          // [16384][1024] bf16
                         float4* __restrict__ out_xlast) {
  if (blockIdx.x < 1024) {
    int w = (blockIdx.x * 256 + threadIdx.x) >> 6;   // 0..4095
    int lane = threadIdx.x & 63;
    int z = w >> 10;           // 0..3
    int e = w & (DD - 1);
    const float* W  = (z == 0) ? Wk  : (z == 1) ? Wv  : (z == 2) ? Wr : Wo;
    const float* tm = (z == 0) ? tmk : (z == 1) ? tmv : tmr;
    unsigned short* dst = (z < 3) ? (wz + (size_t)z * DD * DD + (size_t)e * DD)
                                  : (wo + (size_t)e * DD);
    float s = 0.f;
#pragma unroll
    for (int j = 0; j < 4; ++j) {
      int d = j * 256 + lane * 4;
      float4 wv4 = *(const float4*)(W + (size_t)e * DD + d);
      if (z < 3) {
        float4 t4 = *(const float4*)(tm + d);
        float4 l4 = *(const float4*)(last_x + d);
        s += l4.x * (1.f - t4.x) * wv4.x + l4.y * (1.f - t4.y) * wv4.y +
             l4.z * (1.f - t4.z) * wv4.z + l4.w * (1.f - t4.w) * wv4.w;
        wv4.x *= t4.x; wv4.y *= t4.y; wv4.z *= t4.z; wv4.w *= t4.w;
      }
      ushort4 o;
      o.x = f2bf(wv4.x); o.y = f2bf(wv4.y); o.z = f2bf(wv4.z); o.w = f2bf(wv4.w);
      *(ushort4*)(dst + d) = o;
    }
    if (z < 3) {
      for (int off = 32; off; off >>= 1) s += __shfl_down(s, off, 64);
      if (lane == 0) bias[z * DD + e] = s;
    }
  } else {
    int i = (blockIdx.x - 1024) * 256 + threadIdx.x;  // < MM*DD/4
    float4 v = x[i];
    ushort4 o;
    o.x = f2bf(v.x); o.y = f2bf(v.y); o.z = f2bf(v.z); o.w = f2bf(v.w);
    xb[i] = o;
    int m = i >> 8;                                    // 256 float4 per row
    if ((m & (TT - 1)) == (TT - 1)) {
      int b = m >> 12;
      out_xlast[b * 256 + (i & 255)] = v;
    }
  }
}

// ---------------------------------------------------------------------------
// Fused GEMM1 + WKV, 256-row tile, BK=64, 8 waves, deep-pipelined 3-phase
// (one z per phase) schedule with cross-barrier in-flight global_load_lds,
// swizzled LDS (both-sides: pre-swizzled source + swizzled ds_read), raw
// barriers + counted drain once per K-tile, setprio around MFMA clusters.
__global__ __launch_bounds__(512, 2) void gemm_kvr(
    const unsigned short* __restrict__ A,     // [16384][1024] bf16
    const unsigned short* __restrict__ Wz,    // [3][1024][1024] bf16
    const float* __restrict__ bias,           // [3][1024]
    const float* __restrict__ time_first, const float* __restrict__ time_decay,
    const float* __restrict__ last_num, const float* __restrict__ last_den,
    unsigned short* __restrict__ rwkv,        // [16384][1024] bf16
    float* __restrict__ out_num, float* __restrict__ out_den) {
  // A: [buf][khalf][256 rows][32 bf16] = 64 KiB; B: [buf][khalf][192 rows][32] = 48 KiB
  __shared__ __align__(1024) unsigned short lA[2][2][256 * 32];
  __shared__ __align__(1024) unsigned short lB[2][2][192 * 32];
  const int tid  = threadIdx.x;
  const int lane = tid & 63;
  const int wave = tid >> 6;

  // XCD-aware remap. Grid: 16 x 64 = 1024 blocks; 8 m-stripes x 16 n-zones per XCD.
  const int id  = blockIdx.y * gridDim.x + blockIdx.x;   // 0..1023
  const int xcd = id & 7;
  const int s   = id >> 3;                               // 0..127
  const int m0 = (xcd * 8 + (s >> 4)) * 256;             // m-stripe (256 rows)
  const int n0 = (s & 15) * 64;                          // zone-local col base

  const int wm = (wave >> 1) * 64;   // 4 m-groups of 64
  const int wn = (wave & 1) * 32;    // 2 n-groups of 32
  const int fr = lane & 15;
  const int fq = lane >> 4;

  // ds_read byte offsets (plane-relative, swizzled). Same offset for both k-halves.
  int phA[4], phB[3][2];
#pragma unroll
  for (int m = 0; m < 4; ++m) phA[m] = swz((wm + m * 16 + fr) * 64 + fq * 16);
#pragma unroll
  for (int z = 0; z < 3; ++z)
#pragma unroll
    for (int n = 0; n < 2; ++n)
      phB[z][n] = swz((z * 64 + wn + n * 16 + fr) * 64 + fq * 16);

  // Staging: linear LDS dest (wave-uniform base + lane*16), inverse-swizzled
  // per-lane global source. A plane = 16 KiB = 16 x 1KiB issues (2/wave/khalf);
  // B planes = 2 x 12 KiB = 24 issues (3/wave).
  size_t offA[2][2];
  int dstA[2];
#pragma unroll
  for (int j = 0; j < 2; ++j) {
    int i = wave + j * 8;              // issue block 0..15
    dstA[j] = i * 1024;                // LDS byte base within plane
    int pb = i * 1024 + lane * 16;     // physical byte this lane fills
    int lq = swz(pb);                  // logical byte whose data belongs here
    int r = lq >> 6, cb = lq & 63;
#pragma unroll
    for (int kh = 0; kh < 2; ++kh)
      offA[kh][j] = (size_t)(m0 + r) * DD + kh * 32 + cb / 2;
  }
  size_t offB[3];
  int dstBpl[3], dstBoff[3];
#pragma unroll
  for (int t = 0; t < 3; ++t) {
    int e = wave + t * 8;              // 0..23
    int kh = (e >= 12) ? 1 : 0;
    int i = e - 12 * kh;               // issue block 0..11 within khalf plane
    dstBpl[t]  = kh;
    dstBoff[t] = i * 1024;
    int pb = i * 1024 + lane * 16;
    int lq = swz(pb);
    int r = lq >> 6, cb = lq & 63;     // r in [0,192)
    int z = r >> 6, zr = r & 63;
    offB[t] = (size_t)z * DD * DD + (size_t)(n0 + zr) * DD + kh * 32 + cb / 2;
  }

  f32x4 acc[3][4][2] = {};

  auto stage = [&](int pp, int k0e) {
#pragma unroll
    for (int kh = 0; kh < 2; ++kh)
#pragma unroll
      for (int j = 0; j < 2; ++j)
        async_ld16(A + offA[kh][j] + k0e,
                   (unsigned short*)((char*)lA[pp][kh] + dstA[j]));
#pragma unroll
    for (int t = 0; t < 3; ++t)
      async_ld16(Wz + offB[t] + k0e,
                 (unsigned short*)((char*)lB[pp][dstBpl[t]] + dstBoff[t]));
  };

  // Prologue: stage tile 0 into buf 0, drain, barrier.
  stage(0, 0);
  asm volatile("s_waitcnt vmcnt(0)" ::: "memory");
  __builtin_amdgcn_sched_barrier(0);
  __builtin_amdgcn_s_barrier();

  // One K-tile (BK=64) = 3 phases (z = 0,1,2), 16 MFMA each.
  // Next tile's 7 global_load_lds issue in phase 0 and stay in flight across
  // all intra-quad barriers; single vmcnt(0) drain at quad end (~2 phases later).
  auto quad = [&](int pp, int k0e, bool do_stage) {
    bf16x8 af[4][2];
#pragma unroll
    for (int ks = 0; ks < 2; ++ks)
#pragma unroll
      for (int m = 0; m < 4; ++m)
        af[m][ks] = *(const bf16x8*)((const char*)lA[pp][ks] + phA[m]);
    bf16x8 b0[2][2];
#pragma unroll
    for (int ks = 0; ks < 2; ++ks)
#pragma unroll
      for (int n = 0; n < 2; ++n)
        b0[n][ks] = *(const bf16x8*)((const char*)lB[pp][ks] + phB[0][n]);
    if (do_stage) stage(pp ^ 1, k0e + 64);
    __builtin_amdgcn_s_barrier();
    asm volatile("s_waitcnt lgkmcnt(0)" ::: "memory");
    __builtin_amdgcn_sched_barrier(0);
    __builtin_amdgcn_s_setprio(1);
#pragma unroll
    for (int m = 0; m < 4; ++m)
#pragma unroll
      for (int n = 0; n < 2; ++n)
#pragma unroll
        for (int ks = 0; ks < 2; ++ks)
          acc[0][m][n] = __builtin_amdgcn_mfma_f32_16x16x32_bf16(
              af[m][ks], b0[n][ks], acc[0][m][n], 0, 0, 0);
    __builtin_amdgcn_s_setprio(0);
    __builtin_amdgcn_s_barrier();

    bf16x8 b1[2][2];
#pragma unroll
    for (int ks = 0; ks < 2; ++ks)
#pragma unroll
      for (int n = 0; n < 2; ++n)
        b1[n][ks] = *(const bf16x8*)((const char*)lB[pp][ks] + phB[1][n]);
    __builtin_amdgcn_s_barrier();
    asm volatile("s_waitcnt lgkmcnt(0)" ::: "memory");
    __builtin_amdgcn_sched_barrier(0);
    __builtin_amdgcn_s_setprio(1);
#pragma unroll
    for (int m = 0; m < 4; ++m)
#pragma unroll
      for (int n = 0; n < 2; ++n)
#pragma unroll
        for (int ks = 0; ks < 2; ++ks)
          acc[1][m][n] = __builtin_amdgcn_mfma_f32_16x16x32_bf16(
              af[m][ks], b1[n][ks], acc[1][m][n], 0, 0, 0);
    __builtin_amdgcn_s_setprio(0);
    __builtin_amdgcn_s_barrier();

    bf16x8 b2[2][2];
#pragma unroll
    for (int ks = 0; ks < 2; ++ks)
#pragma unroll
      for (int n = 0; n < 2; ++n)
        b2[n][ks] = *(const bf16x8*)((const char*)lB[pp][ks] + phB[2][n]);
    __builtin_amdgcn_s_barrier();
    asm volatile("s_waitcnt lgkmcnt(0)" ::: "memory");
    __builtin_amdgcn_sched_barrier(0);
    __builtin_amdgcn_s_setprio(1);
#pragma unroll
    for (int m = 0; m < 4; ++m)
#pragma unroll
      for (int n = 0; n < 2; ++n)
#pragma unroll
        for (int ks = 0; ks < 2; ++ks)
          acc[2][m][n] = __builtin_amdgcn_mfma_f32_16x16x32_bf16(
              af[m][ks], b2[n][ks], acc[2][m][n], 0, 0, 0);
    __builtin_amdgcn_s_setprio(0);
    // Single counted drain per K-tile: next tile's stages landed; all waves'
    // LDS reads of this buffer already lgkm-drained above.
    asm volatile("s_waitcnt vmcnt(0)" ::: "memory");
    __builtin_amdgcn_sched_barrier(0);
    __builtin_amdgcn_s_barrier();
  };

#pragma unroll 1
  for (int kt2 = 0; kt2 < 8; ++kt2) {
    quad(0, kt2 * 128, true);
    quad(1, kt2 * 128 + 64, kt2 < 7);
  }

  // Epilogue: WKV in-register. C/D layout: col = lane&15, row = (lane>>4)*4 + reg.
  const int crow = fq * 4;
  const int ccol = fr;
#pragma unroll
  for (int ni = 0; ni < 2; ++ni) {
    int gnz = n0 + wn + ni * 16 + ccol;   // channel d
    float bk = bias[gnz], bv = bias[DD + gnz], br = bias[2 * DD + gnz];
    float tf = time_first[gnz];
    float ln = last_num[gnz], ld = last_den[gnz];
    float dec = __expf(-__expf(time_decay[gnz]));   // hoisted
#pragma unroll
    for (int mi = 0; mi < 4; ++mi) {
#pragma unroll
      for (int r = 0; r < 4; ++r) {
        int gm = m0 + wm + mi * 16 + crow + r;
        float kk = acc[0][mi][ni][r] + bk;
        float vv = acc[1][mi][ni][r] + bv;
        float rr = acc[2][mi][ni][r] + br;
        float efk = __expf(tf + kk);
        float wkv = (ln + efk * vv) * fast_rcp(ld + efk);
        float sr  = fast_rcp(1.0f + __expf(-rr));
        rwkv[(size_t)gm * DD + gnz] = f2bf(sr * wkv);
        if ((gm & (TT - 1)) == (TT - 1)) {
          int b = gm >> 12;
          float ek = __expf(kk);
          out_num[b * DD + gnz] = dec * ln + ek * vv;
          out_den[b * DD + gnz] = dec * ld + ek;
        }
      }
    }
  }
}

// ---------------------------------------------------------------------------
// GEMM2: C[M,N] = A[M,K] @ B[N,K]^T, fp32 out. Two-panel BK=64 (R3 structure)
// + XCD-locality swizzle.
__global__ void gemm_bt128(const unsigned short* __restrict__ A,
                           const unsigned short* __restrict__ Bw,
                           float* __restrict__ Cf,
                           int M, int N, int K) {
  __shared__ unsigned short lA[2][128 * 32];
  __shared__ unsigned short lB[2][128 * 32];
  const int tid  = threadIdx.x;
  const int lane = tid & 63;
  const int wave = tid >> 6;

  // XCD-aware remap: m-stripes partitioned across XCDs, n fastest.
  const int nBlocks = N >> 7;
  const int mBlocks = M >> 7;
  const int id  = blockIdx.y * gridDim.x + blockIdx.x;
  const int xcd = id & 7;
  const int s   = id >> 3;
  const int mPer = mBlocks >> 3;           // m-stripes per XCD (M=16384 -> 16)
  const int m0 = (xcd * mPer + s / nBlocks) * 128;
  const int n0 = (s % nBlocks) * 128;

  const int wm = (wave >> 1) * 64;
  const int wn = (wave & 1) * 64;

  f32x4 acc[4][4] = {};
  const int fr_row = lane & 15;
  const int fr_kb  = (lane >> 4) * 16;
  const int scol = (tid & 3) * 8;

  for (int k0 = 0; k0 < K; k0 += 64) {
    __syncthreads();
#pragma unroll
    for (int h = 0; h < 2; ++h) {
      int kk = k0 + h * 32;
#pragma unroll
      for (int it = 0; it < 2; ++it) {
        int cc  = it * 256 + tid;
        int row = cc >> 2;
        async_ld16(A + (size_t)(m0 + row) * K + (kk + scol),
                   lA[h] + (size_t)(it * 256 + wave * 64) * 8);
      }
#pragma unroll
      for (int it = 0; it < 2; ++it) {
        int cc  = it * 256 + tid;
        int row = cc >> 2;
        async_ld16(Bw + (size_t)(n0 + row) * K + (kk + scol),
                   lB[h] + (size_t)(it * 256 + wave * 64) * 8);
      }
    }
    __syncthreads();

#pragma unroll
    for (int h = 0; h < 2; ++h) {
      bf16x8 af[4], bfr[4];
#pragma unroll
      for (int i = 0; i < 4; ++i) {
        af[i]  = *(const bf16x8*)((const char*)lA[h] + ((wm + i * 16 + fr_row) * 64 + fr_kb));
        bfr[i] = *(const bf16x8*)((const char*)lB[h] + ((wn + i * 16 + fr_row) * 64 + fr_kb));
      }
#pragma unroll
      for (int mi = 0; mi < 4; ++mi)
#pragma unroll
        for (int ni = 0; ni < 4; ++ni)
          acc[mi][ni] = __builtin_amdgcn_mfma_f32_16x16x32_bf16(af[mi], bfr[ni], acc[mi][ni], 0, 0, 0);
    }
  }

  const int crow = (lane >> 4) * 4;
  const int ccol = lane & 15;
#pragma unroll
  for (int mi = 0; mi < 4; ++mi) {
#pragma unroll
    for (int ni = 0; ni < 4; ++ni) {
      int gn = n0 + wn + ni * 16 + ccol;
#pragma unroll
      for (int r = 0; r < 4; ++r) {
        int gm = m0 + wm + mi * 16 + crow + r;
        Cf[(size_t)gm * N + gn] = acc[mi][ni][r];
      }
    }
  }
}

// ---------------------------------------------------------------------------
extern "C" void kernel_launch(void* const* d_in, const int* in_sizes, int n_in,
                              void* d_out, int out_size, void* d_ws, size_t ws_size,
                              hipStream_t stream) {
  const float* x          = (const float*)d_in[0];
  const float* last_x     = (const float*)d_in[1];
  const float* last_num   = (const float*)d_in[2];
  const float* last_den   = (const float*)d_in[3];
  const float* time_decay = (const float*)d_in[4];
  const float* time_first = (const float*)d_in[5];
  const float* tmk        = (const float*)d_in[6];
  const float* tmv        = (const float*)d_in[7];
  const float* tmr        = (const float*)d_in[8];
  const float* Wk         = (const float*)d_in[9];
  const float* Wv         = (const float*)d_in[10];
  const float* Wr         = (const float*)d_in[11];
  const float* Wo         = (const float*)d_in[12];

  float* out       = (float*)d_out;                  // [MM][DD]
  float* out_xlast = out + (size_t)MM * DD;          // [BB][DD]
  float* out_num   = out_xlast + BB * DD;            // [BB][DD]
  float* out_den   = out_num + BB * DD;              // [BB][DD]

  char* ws = (char*)d_ws;
  unsigned short* xb   = (unsigned short*)ws;                 // 33,554,432 B
  unsigned short* wz   = (unsigned short*)(ws + 33554432);    //  6,291,456 B
  unsigned short* wo   = (unsigned short*)(ws + 39845888);    //  2,097,152 B
  float*          bias = (float*)(ws + 41943040);             //     12,288 B
  unsigned short* rwkv = (unsigned short*)(ws + 41955328);    // 33,554,432 B (no alias with xb)

  prep_all<<<1024 + MM * DD / 4 / 256, 256, 0, stream>>>(
      Wk, Wv, Wr, Wo, tmk, tmv, tmr, last_x, (const float4*)x,
      wz, wo, bias, (ushort4*)xb, (float4*)out_xlast);

  // Fused: kvr GEMM + WKV -> rwkv [16384, 1024], plus num/den state rows
  gemm_kvr<<<dim3(16, 64), 512, 0, stream>>>(
      xb, wz, bias, time_first, time_decay, last_num, last_den,
      rwkv, out_num, out_den);

  // out = rwkv @ wo^T : [16384, 1024]
  gemm_bt128<<<dim3(DD / 128, MM / 128), 256, 0, stream>>>(
      rwkv, wo, out, MM, DD, DD);
}